// Round 11
// baseline (133.293 us; speedup 1.0000x reference)
//
#include <hip/hip_runtime.h>
#include <math.h>

#define DEVI __device__ __forceinline__

constexpr int B = 2, P = 16, G = 128, E = 96, N = 128, CO = 2;

DEVI float lrelu(float x) { return x > 0.f ? x : 0.01f * x; }

// ---- workspace layout (floats) ----
// U1: [b][g][n][p]   V1: [b][g][n][e]
constexpr int OFF_U1     = 0;                        // 524288
constexpr int OFF_V1     = OFF_U1 + 524288;          // 3145728
constexpr int OFF_MP110  = OFF_V1 + 3145728;         // 32768  (== me011)
constexpr int OFF_MGP    = OFF_MP110 + 32768;        // 8192   mg110part[bn][2][16] raw
constexpr int OFF_S1P    = OFF_MGP + 8192;           // 49152  s001apart[bn][2][96] raw
constexpr int OFF_RMP    = OFF_S1P + 49152;          // 1024
constexpr int OFF_RMG    = OFF_RMP + 1024;           // 128
constexpr int OFF_RME    = OFF_RMG + 128;            // 512
constexpr int OFF_RMG011 = OFF_RME + 512;            // 384
constexpr int OFF_WT     = OFF_RMG011 + 384;         // 5*16384
constexpr int OFF_PART   = OFF_WT + 81920;           // 256*1664
// part[b][nc][gc][1664]: [0:128)=pm110, [128:896)=psum, [896:1664)=pmax

// ---------------------------------------------------------------------------
// K0: tiny input reductions (R1-proven body) + W1 transpose/fold. 64 blocks.
__global__ void __launch_bounds__(256) k_prep(
    const float* __restrict__ x110, const float* __restrict__ x011,
    const float* __restrict__ W1,
    float* __restrict__ rmpG, float* __restrict__ rmgG,
    float* __restrict__ rmeG, float* __restrict__ rmg011G,
    float* __restrict__ wT) {
  const int blk = blockIdx.x, tid = threadIdx.x;
  if (blk < 56) {                          // wT fold: 81920 elements
    for (int idx = blk * 256 + tid; idx < 81920; idx += 56 * 256) {
      int m = idx >> 14, r = idx & 16383;
      int c = r >> 7, nn = r & 127;
      float v;
      if (m == 0)      v = W1[nn * 128 + c];
      else if (m == 1) v = W1[16384 + nn * 128 + c] + W1[5 * 16384 + nn * 128 + c];
      else if (m == 2) v = W1[2 * 16384 + nn * 128 + c];
      else if (m == 3) v = W1[3 * 16384 + nn * 128 + c];
      else             v = W1[4 * 16384 + nn * 128 + c] + W1[6 * 16384 + nn * 128 + c];
      wT[idx] = v;
    }
  } else {
    int t = (blk - 56) * 256 + tid;        // 0..2047
    if (t < 1024) {                        // rmp[b,c,g] = max_p x110
      int g = t & 127, c = (t >> 7) & 3, b = t >> 9;
      const float* base = x110 + ((b * 4 + c) * P) * G + g;
      float m = -INFINITY;
      for (int p = 0; p < P; p++) m = fmaxf(m, base[p * G]);
      rmpG[t] = m;
    } else if (t < 1152) {                 // rmgS[b,c,p] = max_g x110
      int i = t - 1024;
      int p = i & 15, c = (i >> 4) & 3, b = i >> 6;
      const float* base = x110 + ((b * 4 + c) * P + p) * G;
      float m = -INFINITY;
      for (int g = 0; g < G; g++) m = fmaxf(m, base[g]);
      rmgG[i] = m;
    } else if (t < 1664) {                 // rme[b,c,g] = max_e x011
      int i = t - 1152;
      int g = i & 127, c = (i >> 7) & 1, b = i >> 8;
      const float* base = x011 + ((size_t)(b * 2 + c) * G + g) * E;
      float m = -INFINITY;
      for (int e = 0; e < E; e++) m = fmaxf(m, base[e]);
      rmeG[i] = m;
    } else if (t < 2048) {                 // rmg011[b,c,e] = max_g x011
      int i = t - 1664;
      int e = i % 96; int r = i / 96; int c = r & 1, b = r >> 1;
      const float* base = x011 + ((size_t)(b * 2 + c) * G) * E + e;
      float m = -INFINITY;
      for (int g = 0; g < G; g++) m = fmaxf(m, base[g * E]);
      rmg011G[i] = m;
    }
  }
}

// ---------------------------------------------------------------------------
// K1: layer 0, one block per (b,n,g-half). 512 blocks, ~46KB LDS (2/CU).
__global__ void __launch_bounds__(256) k_layer0(
    const float* __restrict__ x110, const float* __restrict__ x011,
    const float* __restrict__ x001,
    const float* __restrict__ W0_110, const float* __restrict__ b0_110,
    const float* __restrict__ W0_011, const float* __restrict__ b0_011,
    const float* __restrict__ W0_001, const float* __restrict__ b0_001,
    const float* __restrict__ rmpG, const float* __restrict__ rmgG,
    const float* __restrict__ rmeG, const float* __restrict__ rmg011G,
    float* __restrict__ mp110, float* __restrict__ mgp,
    float* __restrict__ s1p) {
  __shared__ float xs[4 * 16 * 64];        // 16KB  x110[b,:,:,ghalf]
  __shared__ float v0h[64 * 97];           // 24.8KB
  __shared__ float u0h[16 * 64];           // 4KB
  __shared__ float rmpL[256], rmeL[128], rmgSL[64], rmg011L[192], x001L[96];
  __shared__ float mpu[64], mev[64], part[256];
  const int blk = blockIdx.x;
  const int b = blk >> 8, n = (blk >> 1) & 127, gh = blk & 1;
  const int bn = b * 128 + n, g0 = gh * 64;
  const int tid = threadIdx.x;

  // stage x110 half: 4096 floats as f4
#pragma unroll
  for (int k = 0; k < 4; k++) {
    int i4 = tid + k * 256;
    int g4 = i4 & 15, p = (i4 >> 4) & 15, cc = i4 >> 8;
    *(float4*)&xs[(cc * 16 + p) * 64 + g4 * 4] =
        *(const float4*)(x110 + ((size_t)(b * 4 + cc) * 16 + p) * 128 + g0 + g4 * 4);
  }
  if (tid < 256) {  // rmpL[cc][g'] (own half)
    int cc = tid >> 6, gp = tid & 63;
    rmpL[tid] = rmpG[b * 512 + cc * 128 + g0 + gp];
  }
  if (tid < 128) {
    int c2 = tid >> 6, gp = tid & 63;
    rmeL[tid] = rmeG[b * 256 + c2 * 128 + g0 + gp];
  }
  if (tid < 64) rmgSL[tid] = rmgG[b * 64 + tid];
  if (tid < 192) rmg011L[tid] = rmg011G[b * 192 + tid];
  if (tid < 96) x001L[tid] = x001[b * 96 + tid];
  __syncthreads();

  float w0[4], w1[4], w2[4];
#pragma unroll
  for (int cc = 0; cc < 4; cc++) {
    w0[cc] = W0_110[n * 4 + cc];
    w1[cc] = W0_110[512 + n * 4 + cc];
    w2[cc] = W0_110[1024 + n * 4 + cc];
  }
  float we0 = W0_011[512 + n * 2], we1 = W0_011[512 + n * 2 + 1];
  float bu = b0_110[n] + b0_110[128 + n] + b0_110[256 + n] + b0_011[256 + n];
  float vw00 = W0_011[n * 2], vw01 = W0_011[n * 2 + 1];
  float vw10 = W0_011[256 + n * 2], vw11 = W0_011[256 + n * 2 + 1];
  float w001 = W0_001[n];
  float bv = b0_011[n] + b0_011[128 + n] + b0_001[n];

#pragma unroll
  for (int k = 0; k < 4; k++) {            // U0 half-row (p, g')
    int i = tid + k * 256, p = i >> 6, gp = i & 63;
    float acc = bu + we0 * rmeL[gp] + we1 * rmeL[64 + gp];
#pragma unroll
    for (int cc = 0; cc < 4; cc++)
      acc += w0[cc] * xs[(cc * 16 + p) * 64 + gp] + w1[cc] * rmpL[cc * 64 + gp]
           + w2[cc] * rmgSL[cc * 16 + p];
    u0h[i] = acc;
  }
  {                                        // V0 half-row (g', e)
    const float* xa = x011 + (size_t)(b * 2) * 12288;
    const float* xb = xa + 12288;
#pragma unroll
    for (int k = 0; k < 24; k++) {
      int i = tid + k * 256;
      int gp = i / 96, e = i - gp * 96;
      int g = g0 + gp;
      float val = bv + vw00 * xa[g * 96 + e] + vw01 * xb[g * 96 + e]
                + vw10 * rmg011L[e] + vw11 * rmg011L[96 + e] + w001 * x001L[e];
      v0h[gp * 97 + e] = val;
    }
  }
  __syncthreads();
  {                                        // mev partials: 64 g' x 4 quarters
    int gp = tid & 63, q = tid >> 6;
    const float* r = &v0h[gp * 97 + q * 24];
    float m = -INFINITY;
    for (int j = 0; j < 24; j++) m = fmaxf(m, r[j]);
    part[q * 64 + gp] = m;
  }
  if (tid < 64) {                          // mpu (u0h ready)
    float m = -INFINITY;
    for (int p = 0; p < P; p++) m = fmaxf(m, u0h[p * 64 + tid]);
    mpu[tid] = m;
  }
  __syncthreads();
  if (tid < 64) {
    float m = fmaxf(fmaxf(part[tid], part[64 + tid]),
                    fmaxf(part[128 + tid], part[192 + tid]));
    mev[tid] = m;
    mp110[bn * 128 + g0 + tid] = lrelu(mpu[tid] + m);
  }
  __syncthreads();
  {                                        // mg110 raw partial over own g'
    int p = tid >> 4, ch = tid & 15;
    float m = -INFINITY;
    for (int gp = ch * 4; gp < ch * 4 + 4; gp++)
      m = fmaxf(m, u0h[p * 64 + gp] + mev[gp]);
    part[tid] = m;
  }
  __syncthreads();
  if (tid < 16) {
    float m = -INFINITY;
    for (int ch = 0; ch < 16; ch++) m = fmaxf(m, part[tid * 16 + ch]);
    mgp[(bn * 2 + gh) * 16 + tid] = m;     // raw (pre-lrelu)
  }
  if (tid < 96) {                          // s001a raw partial
    float m = -INFINITY;
    for (int gp = 0; gp < 64; gp++)
      m = fmaxf(m, mpu[gp] + v0h[gp * 97 + tid]);
    s1p[(bn * 2 + gh) * 96 + tid] = m;     // raw
  }
}

// ---------------------------------------------------------------------------
// K2: layer 1, one block per (b,g,n-half). 512 blocks, 256 thr (~70KB LDS).
// Recomputes raw U0/V0 at g -> mpu/mev -> s110/s011, then GEMMs for 64 n.
__global__ void __launch_bounds__(256) k_layer1(
    const float* __restrict__ x110, const float* __restrict__ x011,
    const float* __restrict__ x001,
    const float* __restrict__ W0_110, const float* __restrict__ b0_110,
    const float* __restrict__ W0_011, const float* __restrict__ b0_011,
    const float* __restrict__ W0_001, const float* __restrict__ b0_001,
    const float* __restrict__ rmpG, const float* __restrict__ rmgG,
    const float* __restrict__ rmeG, const float* __restrict__ rmg011G,
    const float* __restrict__ wT,
    float* __restrict__ U1, float* __restrict__ V1) {
  __shared__ float s110c[128 * 16];        // raw U0 then s110
  __shared__ float s011c[128 * 96];        // raw V0 then s011
  __shared__ float W0L110[1536], W0L011[768], W0L001[128];
  __shared__ float busum[128], bvsum[128], mpu[128], mev[128];
  __shared__ float x011row[192], rmg011s[192], x001s[96];
  __shared__ float x110col[64], rmg110p[64], rmp4[4], rme2[2];
  __shared__ float partM[256];
  const int blk = blockIdx.x;
  const int b = blk >> 8, g = (blk >> 1) & 127, nh = blk & 1;
  const int n0 = nh * 64;
  const int tid = threadIdx.x;

  for (int i = tid; i < 1536; i += 256) W0L110[i] = W0_110[i];
  for (int i = tid; i < 768; i += 256) W0L011[i] = W0_011[i];
  if (tid < 128) {
    W0L001[tid] = W0_001[tid];
    busum[tid] = b0_110[tid] + b0_110[128 + tid] + b0_110[256 + tid]
               + b0_011[256 + tid];
    bvsum[tid] = b0_011[tid] + b0_011[128 + tid] + b0_001[tid];
  }
  if (tid < 192) {
    int c = tid / 96, e = tid % 96;
    x011row[tid] = x011[((size_t)(b * 2 + c) * 128 + g) * 96 + e];
    rmg011s[tid] = rmg011G[b * 192 + tid];
  }
  if (tid < 96) x001s[tid] = x001[b * 96 + tid];
  if (tid < 64) {
    int c = tid >> 4, p = tid & 15;
    x110col[tid] = x110[((size_t)(b * 4 + c) * 16 + p) * 128 + g];
    rmg110p[tid] = rmgG[b * 64 + tid];
  }
  if (tid < 4) rmp4[tid] = rmpG[(b * 4 + tid) * 128 + g];
  if (tid < 2) rme2[tid] = rmeG[(b * 2 + tid) * 128 + g];
  __syncthreads();

#pragma unroll
  for (int k = 0; k < 8; k++) {            // raw U0 column (c,p)
    int i = tid + k * 256, c = i >> 4, p = i & 15;
    float acc = busum[c] + W0L011[512 + c * 2] * rme2[0]
              + W0L011[512 + c * 2 + 1] * rme2[1];
#pragma unroll
    for (int cc = 0; cc < 4; cc++)
      acc += W0L110[c * 4 + cc] * x110col[cc * 16 + p]
           + W0L110[512 + c * 4 + cc] * rmp4[cc]
           + W0L110[1024 + c * 4 + cc] * rmg110p[cc * 16 + p];
    s110c[i] = acc;
  }
  for (int k = 0; k < 48; k++) {           // raw V0 column (c,e)
    int i = tid + k * 256;
    int c = i / 96, e = i - c * 96;
    float v = bvsum[c]
            + W0L011[c * 2] * x011row[e] + W0L011[c * 2 + 1] * x011row[96 + e]
            + W0L011[256 + c * 2] * rmg011s[e]
            + W0L011[256 + c * 2 + 1] * rmg011s[96 + e]
            + W0L001[c] * x001s[e];
    s011c[i] = v;
  }
  __syncthreads();
  if (tid < 128) {                         // mpu[c] = max_p raw U0
    float m = -INFINITY;
    for (int p = 0; p < P; p++) m = fmaxf(m, s110c[tid * 16 + p]);
    mpu[tid] = m;
  }
  {                                        // mev partials: (c, half-e)
    int c = tid >> 1, h = tid & 1;
    const float* r = &s011c[c * 96 + h * 48];
    float m = -INFINITY;
    for (int j = 0; j < 48; j++) m = fmaxf(m, r[j]);
    partM[tid] = m;
  }
  __syncthreads();
  if (tid < 128) mev[tid] = fmaxf(partM[tid * 2], partM[tid * 2 + 1]);
  __syncthreads();
#pragma unroll
  for (int k = 0; k < 8; k++) {            // activate s110
    int i = tid + k * 256, c = i >> 4;
    s110c[i] = lrelu(s110c[i] + mev[c]);
  }
  for (int k = 0; k < 48; k++) {           // activate s011
    int i = tid + k * 256, c = i / 96;
    s011c[i] = lrelu(s011c[i] + mpu[c]);
  }
  __syncthreads();

  const float* w0T = wT;
  const float* w3T = wT + 3 * 16384;

  // ---- V1: 2n x 12e per thread, 64 n of this half ----
  {
    int np = tid >> 3, e0 = (tid & 7) * 12;
    int na = n0 + np * 2, nb = na + 1;
    float4 aA[3], aB[3];
#pragma unroll
    for (int k = 0; k < 3; k++) {
      aA[k] = make_float4(0.f, 0.f, 0.f, 0.f);
      aB[k] = make_float4(0.f, 0.f, 0.f, 0.f);
    }
    for (int c = 0; c < 128; c++) {
      float2 wv = *(const float2*)&w3T[c * 128 + na];
      float4 s0 = *(const float4*)&s011c[c * 96 + e0];
      float4 s1 = *(const float4*)&s011c[c * 96 + e0 + 4];
      float4 s2 = *(const float4*)&s011c[c * 96 + e0 + 8];
      aA[0].x += wv.x * s0.x; aA[0].y += wv.x * s0.y;
      aA[0].z += wv.x * s0.z; aA[0].w += wv.x * s0.w;
      aA[1].x += wv.x * s1.x; aA[1].y += wv.x * s1.y;
      aA[1].z += wv.x * s1.z; aA[1].w += wv.x * s1.w;
      aA[2].x += wv.x * s2.x; aA[2].y += wv.x * s2.y;
      aA[2].z += wv.x * s2.z; aA[2].w += wv.x * s2.w;
      aB[0].x += wv.y * s0.x; aB[0].y += wv.y * s0.y;
      aB[0].z += wv.y * s0.z; aB[0].w += wv.y * s0.w;
      aB[1].x += wv.y * s1.x; aB[1].y += wv.y * s1.y;
      aB[1].z += wv.y * s1.z; aB[1].w += wv.y * s1.w;
      aB[2].x += wv.y * s2.x; aB[2].y += wv.y * s2.y;
      aB[2].z += wv.y * s2.z; aB[2].w += wv.y * s2.w;
    }
    float* dA = V1 + ((size_t)((b * 128 + g) * 128 + na)) * 96 + e0;
    float* dB = dA + 96;
#pragma unroll
    for (int k = 0; k < 3; k++) {
      *(float4*)(dA + k * 4) = aA[k];
      *(float4*)(dB + k * 4) = aB[k];
    }
  }
  // ---- U1: 1n x 4p per thread -> layout [b][g][n][p], float4 store ----
  {
    int nn = tid >> 2, pq = tid & 3;
    int n = n0 + nn;
    float4 a = make_float4(0.f, 0.f, 0.f, 0.f);
    const float* sr = &s110c[pq * 4];
    for (int c = 0; c < 128; c++) {
      float w0v = w0T[c * 128 + n];
      float4 s = *(const float4*)&sr[c * 16];
      a.x += w0v * s.x; a.y += w0v * s.y; a.z += w0v * s.z; a.w += w0v * s.w;
    }
    *(float4*)(U1 + ((size_t)((b * 128 + g) * 128 + n)) * 16 + pq * 4) = a;
  }
}

// ---------------------------------------------------------------------------
// K3: partial g-reduction. grid = (b, nc of 8n, gc of 16g) = 256 blocks.
__global__ void __launch_bounds__(256) k_post3(
    const float* __restrict__ U1, const float* __restrict__ V1,
    const float* __restrict__ s1p, const float* __restrict__ mp110,
    const float* __restrict__ mgp,
    const float* __restrict__ wT, const float* __restrict__ b1,
    float* __restrict__ partOut) {
  constexpr int GS = 16;
  __shared__ float Vt[GS][8][104];
  __shared__ float Ut[GS][16][9];
  __shared__ float bfL[8][GS];
  __shared__ float egL[8][96];
  __shared__ float cpL[8][16];
  __shared__ float partE[GS][8][4];
  __shared__ float mxeV[GS][8], mxpU[GS][8];
  __shared__ float bbL[8], bvL[8];
  const int blk = blockIdx.x;
  const int b = blk >> 7, nc = (blk >> 3) & 15, gc = blk & 7;
  const int n0 = nc * 8, g0 = gc * 16;
  const int tid = threadIdx.x;
  const float* w15T = wT + 16384;
  const float* w2T  = wT + 2 * 16384;
  const float* w46T = wT + 4 * 16384;

  if (tid < 8) {
    int n = n0 + tid;
    bbL[tid] = b1[n] + b1[128 + n] + b1[256 + n] + b1[640 + n];
    bvL[tid] = b1[384 + n] + b1[512 + n] + b1[768 + n];
  }
  if (tid < 128) {   // bf[nn][gl]
    int nn = tid >> 4, gl = tid & 15;
    float acc = 0.f;
    for (int c = 0; c < 128; c++)
      acc += w15T[c * 128 + n0 + nn] * mp110[(b * 128 + c) * 128 + g0 + gl];
    bfL[nn][gl] = acc;
  } else {           // cp[nn][p], mg110 folded from raw halves
    int i = tid - 128;
    int nn = i >> 4, p = i & 15;
    float acc = 0.f;
    for (int c = 0; c < 128; c++) {
      float m = fmaxf(mgp[(b * 128 + c) * 32 + p], mgp[(b * 128 + c) * 32 + 16 + p]);
      acc += w2T[c * 128 + n0 + nn] * lrelu(m);
    }
    cpL[nn][p] = acc;
  }
#pragma unroll
  for (int k = 0; k < 3; k++) {   // eg[nn][e], s001a folded from raw halves
    int s = tid + k * 256;
    int nn = s / 96, e = s % 96;
    float acc = 0.f;
    for (int c = 0; c < 128; c++) {
      float m = fmaxf(s1p[(b * 128 + c) * 192 + e], s1p[(b * 128 + c) * 192 + 96 + e]);
      acc += w46T[c * 128 + n0 + nn] * lrelu(m);
    }
    egL[nn][e] = acc;
  }
  __syncthreads();

  const size_t Ubase = (size_t)b * 128 * 128 * 16;
  const size_t Vbase = (size_t)b * 128 * 128 * 96;
#pragma unroll
  for (int k = 0; k < 12; k++) {   // stage V (+bv+eg), float4
    int i4 = tid + k * 256;
    int gs = i4 / 192, r = i4 % 192, nn = r / 24, e4 = r % 24;
    float4 v = *(const float4*)(V1 + Vbase
                 + ((size_t)(g0 + gs) * 128 + n0 + nn) * 96 + e4 * 4);
    float bvv = bvL[nn];
    const float* eg = &egL[nn][e4 * 4];
    float4 o = make_float4(v.x + bvv + eg[0], v.y + bvv + eg[1],
                           v.z + bvv + eg[2], v.w + bvv + eg[3]);
    *(float4*)&Vt[gs][nn][e4 * 4] = o;
  }
#pragma unroll
  for (int k = 0; k < 2; k++) {    // stage U from [b][g][n][p] (+bb+cp+bf)
    int i4 = tid + k * 256;        // 512 f4
    int gs = i4 >> 5, r = i4 & 31, nn = r >> 2, p4 = r & 3;
    float4 u = *(const float4*)(U1 + Ubase
                 + ((size_t)(g0 + gs) * 128 + n0 + nn) * 16 + p4 * 4);
    float base = bbL[nn] + bfL[nn][gs];
    Ut[gs][p4 * 4 + 0][nn] = u.x + base + cpL[nn][p4 * 4 + 0];
    Ut[gs][p4 * 4 + 1][nn] = u.y + base + cpL[nn][p4 * 4 + 1];
    Ut[gs][p4 * 4 + 2][nn] = u.z + base + cpL[nn][p4 * 4 + 2];
    Ut[gs][p4 * 4 + 3][nn] = u.w + base + cpL[nn][p4 * 4 + 3];
  }
  __syncthreads();
#pragma unroll
  for (int k = 0; k < 2; k++) {    // partial max_e
    int i = tid + k * 256;
    int gs = i >> 5, nn = (i >> 2) & 7, ec = i & 3;
    float m = -INFINITY;
    for (int e = ec * 24; e < ec * 24 + 24; e++) m = fmaxf(m, Vt[gs][nn][e]);
    partE[gs][nn][ec] = m;
  }
  __syncthreads();
  if (tid < 128) {
    int gs = tid >> 3, nn = tid & 7;
    mxeV[gs][nn] = fmaxf(fmaxf(partE[gs][nn][0], partE[gs][nn][1]),
                         fmaxf(partE[gs][nn][2], partE[gs][nn][3]));
    float m = -INFINITY;
    for (int p = 0; p < 16; p++) m = fmaxf(m, Ut[gs][p][nn]);
    mxpU[gs][nn] = m;
  }
  __syncthreads();

  float* pb = partOut + (size_t)blk * 1664;
  if (tid < 128) {
    int nn = tid >> 4, p = tid & 15;
    float a = 0.f;
#pragma unroll
    for (int gs = 0; gs < GS; gs++)
      a += lrelu(Ut[gs][p][nn] + mxeV[gs][nn]);
    pb[tid] = a;
  }
#pragma unroll
  for (int k = 0; k < 3; k++) {
    int s = tid + k * 256;
    int nn = s / 96, e = s % 96;
    float a = 0.f, m = -INFINITY;
#pragma unroll
    for (int gs = 0; gs < GS; gs++) {
      float pre = mxpU[gs][nn] + Vt[gs][nn][e];
      a += lrelu(pre);
      m = fmaxf(m, pre);
    }
    pb[128 + s] = a;
    pb[896 + s] = m;
  }
}

// ---------------------------------------------------------------------------
// K4: heads + partial-fold. One block per (b,o), 256 thr. [R10-proven]
__global__ void __launch_bounds__(256) k_final(
    const float* __restrict__ partIn,
    const float* __restrict__ Wact, const float* __restrict__ bact,
    const float* __restrict__ Wcrit, const float* __restrict__ bcrit,
    float* __restrict__ out) {
  __shared__ float buf[128][97];
  __shared__ float m110s[128][17];
  __shared__ float sm011[N], sm001[N], sce1[E], sce[E], scp[P], srow[P], scol[E];
  const int bo = blockIdx.x;
  const int o = bo & 1, b = bo >> 1;
  const int t = threadIdx.x;
  const float* pbB = partIn + (size_t)(b * 16) * 8 * 1664;

#pragma unroll
  for (int k = 0; k < 8; k++) {
    int i = t + k * 256;
    int nc = i >> 7, j = i & 127;
    const float* base = pbB + (size_t)(nc * 8) * 1664;
    float a = 0.f;
#pragma unroll
    for (int gc = 0; gc < 8; gc++) a += base[gc * 1664 + j];
    m110s[nc * 8 + (j >> 4)][j & 15] = a * (1.f / G);
  }
#pragma unroll
  for (int k = 0; k < 48; k++) {
    int i = t + k * 256;
    int nc = i / 768, r = i % 768;
    const float* base = pbB + (size_t)(nc * 8) * 1664;
    float a = 0.f;
#pragma unroll
    for (int gc = 0; gc < 8; gc++) a += base[gc * 1664 + 128 + r];
    buf[nc * 8 + r / 96][r % 96] = a * (1.f / G);
  }
  __syncthreads();
  if (t < 128) {
    float s = 0.f;
    for (int e = 0; e < E; e++) s += buf[t][e];
    sm011[t] = s * (1.f / E);
  }
  if (t < 96) {
    const float* wc1 = Wcrit + (1 * CO + o) * N;
    float c = 0.f;
    for (int n = 0; n < N; n++) c += wc1[n] * buf[n][t];
    sce1[t] = c;
  }
  __syncthreads();
#pragma unroll
  for (int k = 0; k < 48; k++) {
    int i = t + k * 256;
    int nc = i / 768, r = i % 768;
    const float* base = pbB + (size_t)(nc * 8) * 1664;
    float m = -INFINITY;
#pragma unroll
    for (int gc = 0; gc < 8; gc++) m = fmaxf(m, base[gc * 1664 + 896 + r]);
    buf[nc * 8 + r / 96][r % 96] = lrelu(m);
  }
  __syncthreads();
  if (t < 128) {
    float s = 0.f;
    for (int e = 0; e < E; e++) s += buf[t][e];
    sm001[t] = s * (1.f / E);
  }
  if (t < 96) {
    const float* wc2 = Wcrit + (2 * CO + o) * N;
    float c = 0.f;
    for (int n = 0; n < N; n++) c += wc2[n] * buf[n][t];
    sce[t] = sce1[t] + c + bcrit[CO + o] + bcrit[2 * CO + o];
  }
  __syncthreads();
  if (t < P) {
    const float* wa0 = Wact + o * N;
    const float* wa1 = Wact + (1 * CO + o) * N;
    const float* wa2 = Wact + (2 * CO + o) * N;
    const float* wc0 = Wcrit + o * N;
    float a = 0.f, c = 0.f, aa = 0.f;
    for (int n = 0; n < N; n++) {
      float m = m110s[n][t];
      a += wa0[n] * m;
      c += wc0[n] * m;
      aa += wa1[n] * sm011[n] + wa2[n] * sm001[n];
    }
    float act = a + aa + bact[o] + bact[CO + o] + bact[2 * CO + o];
    out[(b * CO + o) * P + t] = lrelu(act);
    scp[t] = c + bcrit[o];
  }
  __syncthreads();
  if (t < P) {
    float m = -INFINITY;
    for (int e = 0; e < E; e++) m = fmaxf(m, lrelu(scp[t] + sce[e]));
    srow[t] = m;
  } else if (t < P + E) {
    int e = t - P;
    float m = -INFINITY;
    for (int p = 0; p < P; p++) m = fmaxf(m, lrelu(scp[p] + sce[e]));
    scol[e] = m;
  }
  __syncthreads();
  if (t == 0) {
    float v110 = 0.f, v011 = 0.f;
    for (int p = 0; p < P; p++) v110 += srow[p];
    for (int e = 0; e < E; e++) v011 += scol[e];
    out[B * CO * P + b * CO + o] = 2.f + v110 + 2.f * v011;
  }
}

extern "C" void kernel_launch(void* const* d_in, const int* in_sizes, int n_in,
                              void* d_out, int out_size, void* d_ws, size_t ws_size,
                              hipStream_t stream) {
  const float* x110   = (const float*)d_in[0];
  const float* x011   = (const float*)d_in[1];
  const float* x001   = (const float*)d_in[2];
  const float* W0_110 = (const float*)d_in[3];
  const float* b0_110 = (const float*)d_in[4];
  const float* W0_011 = (const float*)d_in[5];
  const float* b0_011 = (const float*)d_in[6];
  const float* W0_001 = (const float*)d_in[7];
  const float* b0_001 = (const float*)d_in[8];
  const float* W1     = (const float*)d_in[9];
  const float* b1     = (const float*)d_in[10];
  const float* Wact   = (const float*)d_in[11];
  const float* bact   = (const float*)d_in[12];
  const float* Wcrit  = (const float*)d_in[13];
  const float* bcrit  = (const float*)d_in[14];
  float* out = (float*)d_out;
  float* w = (float*)d_ws;

  float* U1     = w + OFF_U1;
  float* V1     = w + OFF_V1;
  float* mp110  = w + OFF_MP110;
  float* mgp    = w + OFF_MGP;
  float* s1p    = w + OFF_S1P;
  float* rmpG   = w + OFF_RMP;
  float* rmgG   = w + OFF_RMG;
  float* rmeG   = w + OFF_RME;
  float* rmg011 = w + OFF_RMG011;
  float* wT     = w + OFF_WT;
  float* partB  = w + OFF_PART;

  k_prep<<<64, 256, 0, stream>>>(x110, x011, W1, rmpG, rmgG, rmeG, rmg011, wT);
  k_layer0<<<512, 256, 0, stream>>>(x110, x011, x001, W0_110, b0_110, W0_011,
                                    b0_011, W0_001, b0_001,
                                    rmpG, rmgG, rmeG, rmg011,
                                    mp110, mgp, s1p);
  k_layer1<<<512, 256, 0, stream>>>(x110, x011, x001, W0_110, b0_110, W0_011,
                                    b0_011, W0_001, b0_001,
                                    rmpG, rmgG, rmeG, rmg011, wT, U1, V1);
  k_post3<<<256, 256, 0, stream>>>(U1, V1, s1p, mp110, mgp, wT, b1, partB);
  k_final<<<4, 256, 0, stream>>>(partB, Wact, bact, Wcrit, bcrit, out);
}